// Round 14
// baseline (2828.564 us; speedup 1.0000x reference)
//
#include <hip/hip_runtime.h>
#include <hip/hip_bf16.h>
#include <math.h>

// Problem dims
#define BB 2
#define LL 2048
#define DD 768
#define HH 12
#define EE 32
#define RR 57
#define NN 20
#define PP 248
#define MM 256          // P padded to 256 for MFMA tiles
#define KS 8            // K-split in context GEMM
#define KCH (LL / KS)   // 256

// ATTRIBUTION PROBE: idempotent internal repeats to surface per-kernel time
// in rocprof top-5 (fills sit at ~247us; these push each kernel above that).
#define REP_P 64
#define REP_G 96
#define REP_S 128

// ws layout (float offsets)
#define ENT_EMB_OFF 0                          // f32 B*E*D
#define A16_OFF   (BB * EE * DD)               // bf16 [B][MM][LL] (unnormalized q)
#define A16_F     (BB * MM * LL / 2)
#define CPART_OFF (A16_OFF + A16_F)            // bf16 [KS][B][MM][DD]

#define PT4 4
#define NPT4 62

// kP grid roles
#define NQBLK (BB * 256)          // 512 q blocks (8-l chunks), XCD-swizzled
#define NEBLK (EE * BB)           // 64 ent_emb blocks
#define ASTRIDE 388               // att_s row stride (floats)

typedef __attribute__((ext_vector_type(8))) short bf16x8;
typedef __attribute__((ext_vector_type(4))) float f32x4;

__device__ __forceinline__ unsigned short f2bf(float f) {
    __hip_bfloat16 h = __float2bfloat16(f);
    return __builtin_bit_cast(unsigned short, h);
}
__device__ __forceinline__ float bf2f(unsigned short u) {
    unsigned int x = ((unsigned int)u) << 16;
    return __builtin_bit_cast(float, x);
}
__device__ __forceinline__ void pair_so(int p, int& s, int& o) {
    s = p / 31;
    int r = p - s * 31;
    o = (r < s) ? r : r + 1;
}
__device__ __forceinline__ float dot4(float4 a, float4 b) {
    return a.x * b.x + a.y * b.y + a.z * b.z + a.w * b.w;
}

// ===== Kernel P: role Q (att gather -> q rows, XCD-swizzled), role E =====
__global__ __launch_bounds__(256) void kP(const float* __restrict__ seq,
                                          const float* __restrict__ att,
                                          const int* __restrict__ spans,
                                          float* __restrict__ ws) {
    __shared__ __align__(16) float att_s[8][ASTRIDE];
    __shared__ int sp_s[EE];
    int bid = blockIdx.x;
    int t = threadIdx.x;

    if (bid < NQBLK) {
        int xcd = bid & 7, i = bid >> 3;
        int chunk = xcd * (NQBLK / 8) + i;       // 0..511
        int b = chunk >> 8, l0 = (chunk & 255) * 8;
        for (int rep = 0; rep < REP_P; ++rep) {
            __syncthreads();   // previous rep's readers done before re-staging
            if (t < EE) sp_s[t] = spans[b * EE + t];
            __syncthreads();
            for (int i2 = t; i2 < EE * HH * 2; i2 += 256) {
                int seg = i2 & 1, eh = i2 >> 1;
                int e = eh / HH, h = eh - e * HH;
                const float* base = att + ((size_t)(b * HH + h) * LL + sp_s[e]) * LL + l0 + seg * 4;
                float4 v0 = *(const float4*)base;
                float4 v1 = *(const float4*)(base + LL);
                float4 v2 = *(const float4*)(base + 2 * LL);
                float4 v3 = *(const float4*)(base + 3 * LL);
                att_s[seg * 4 + 0][eh] = 0.25f * (v0.x + v1.x + v2.x + v3.x);
                att_s[seg * 4 + 1][eh] = 0.25f * (v0.y + v1.y + v2.y + v3.y);
                att_s[seg * 4 + 2][eh] = 0.25f * (v0.z + v1.z + v2.z + v3.z);
                att_s[seg * 4 + 3][eh] = 0.25f * (v0.w + v1.w + v2.w + v3.w);
            }
            __syncthreads();
            int p = t, s, o;
            pair_so(p, s, o);
            float q[8];
            #pragma unroll
            for (int l = 0; l < 8; ++l) {
                float4 a0 = *(const float4*)&att_s[l][s * HH];
                float4 a1 = *(const float4*)&att_s[l][s * HH + 4];
                float4 a2 = *(const float4*)&att_s[l][s * HH + 8];
                float4 b0 = *(const float4*)&att_s[l][o * HH];
                float4 b1 = *(const float4*)&att_s[l][o * HH + 4];
                float4 b2 = *(const float4*)&att_s[l][o * HH + 8];
                q[l] = dot4(a0, b0) + dot4(a1, b1) + dot4(a2, b2);
            }
            unsigned short* A16 = (unsigned short*)(ws + A16_OFF) + (size_t)(b * MM + p) * LL + l0;
            #pragma unroll
            for (int i2 = 0; i2 < 2; ++i2) {
                ushort4 ov = make_ushort4(f2bf(q[i2 * 4 + 0]), f2bf(q[i2 * 4 + 1]),
                                          f2bf(q[i2 * 4 + 2]), f2bf(q[i2 * 4 + 3]));
                *(ushort4*)(A16 + i2 * 4) = ov;
            }
        }
    } else {
        int bx = bid - NQBLK;
        int e = bx & 31, b = bx >> 5;
        int st = spans[b * EE + e];
        float* ee = ws + ENT_EMB_OFF + (size_t)(b * EE + e) * DD;
        const float* srow = seq + (size_t)(b * LL + st) * DD;
        for (int d = t; d < DD; d += 256) {
            ee[d] = 0.25f * (srow[d] + srow[DD + d] + srow[2 * DD + d] + srow[3 * DD + d]);
        }
    }
}

// Kernel 3: cpart[ks][b][m][n] (bf16) = sum_{k in split} A[m][k] * seq[k][n]
__global__ __launch_bounds__(256) void k3_gemm(const float* __restrict__ seq,
                                               float* __restrict__ ws) {
    int m0 = blockIdx.x * 64, n0 = blockIdx.y * 64;
    int ks = blockIdx.z & (KS - 1), b = blockIdx.z >> 3;
    const unsigned short* A = (const unsigned short*)(ws + A16_OFF) + (size_t)b * MM * LL;
    __shared__ __align__(16) short As[64][40];
    __shared__ __align__(16) short Bs[64][40];
    int t = threadIdx.x;
    int row = t >> 2, seg = t & 3;
    int bl = t >> 3, bd = t & 7;
    int w = t >> 6, lane = t & 63;
    int wr = w >> 1, wc = w & 1;
    int fr = lane & 15, kb = lane >> 4;
    int k0c = ks * KCH;
    for (int rep = 0; rep < REP_G; ++rep) {
        f32x4 acc[2][2] = {};
        __syncthreads();
        for (int st = 0; st < KCH / 32; ++st) {
            int kk = k0c + st * 32;
            *(uint4*)&As[row][seg * 8] = *(const uint4*)(A + (size_t)(m0 + row) * LL + kk + seg * 8);
            {
                const float* sp2 = seq + (size_t)(b * LL + kk + bl) * DD + n0 + bd * 8;
                float4 u0 = *(const float4*)sp2;
                float4 u1 = *(const float4*)(sp2 + 4);
                unsigned short bv[8] = {f2bf(u0.x), f2bf(u0.y), f2bf(u0.z), f2bf(u0.w),
                                        f2bf(u1.x), f2bf(u1.y), f2bf(u1.z), f2bf(u1.w)};
                #pragma unroll
                for (int i = 0; i < 8; ++i) {
                    int k = (i + bd) & 7;       // stagger: 16-way -> 2-way bank conflict
                    Bs[bd * 8 + k][bl] = (short)bv[k];
                }
            }
            __syncthreads();
            bf16x8 af[2], bfr[2];
            #pragma unroll
            for (int i = 0; i < 2; ++i) af[i] = *(bf16x8*)&As[wr * 32 + i * 16 + fr][kb * 8];
            #pragma unroll
            for (int j = 0; j < 2; ++j) bfr[j] = *(bf16x8*)&Bs[wc * 32 + j * 16 + fr][kb * 8];
            #pragma unroll
            for (int i = 0; i < 2; ++i)
                #pragma unroll
                for (int j = 0; j < 2; ++j)
                    acc[i][j] = __builtin_amdgcn_mfma_f32_16x16x32_bf16(af[i], bfr[j], acc[i][j], 0, 0, 0);
            __syncthreads();
        }
        unsigned short* cp =
            (unsigned short*)(ws + CPART_OFF) + (size_t)((ks * BB + b) * MM) * DD;
        #pragma unroll
        for (int i = 0; i < 2; ++i)
            #pragma unroll
            for (int j = 0; j < 2; ++j)
                #pragma unroll
                for (int r = 0; r < 4; ++r) {
                    int gm = m0 + wr * 32 + i * 16 + kb * 4 + r;
                    int gn = n0 + wc * 32 + j * 16 + fr;
                    cp[(size_t)gm * DD + gn] = f2bf(acc[i][j][r]);
                }
    }
}

// Kernel 4: qsum + register emb (cpart bf16) + scoring; rows split across 2 z-groups
__global__ __launch_bounds__(256, 1) void k4_score(const float* __restrict__ rel,
                                                   const float* __restrict__ nota,
                                                   const float* __restrict__ ws,
                                                   float* __restrict__ out) {
    int pt = blockIdx.x, b = blockIdx.y, gz = blockIdx.z;
    int tid = threadIdx.x, w = tid >> 6, lane = tid & 63;
    __shared__ float red_s[4][PT4];
    __shared__ float qs_s[PT4];
    __shared__ float nota_s[PT4][NN];
    for (int rep = 0; rep < REP_S; ++rep) {
        __syncthreads();   // previous rep fully done before smem rewrite
        {
            const unsigned short* A16 =
                (const unsigned short*)(ws + A16_OFF) + (size_t)(b * MM + pt * PT4) * LL;
            #pragma unroll
            for (int j = 0; j < PT4; ++j) {
                ushort4 u0 = *(const ushort4*)(A16 + (size_t)j * LL + tid * 8);
                ushort4 u1 = *(const ushort4*)(A16 + (size_t)j * LL + tid * 8 + 4);
                float v = bf2f(u0.x) + bf2f(u0.y) + bf2f(u0.z) + bf2f(u0.w)
                        + bf2f(u1.x) + bf2f(u1.y) + bf2f(u1.z) + bf2f(u1.w);
                #pragma unroll
                for (int off = 32; off > 0; off >>= 1) v += __shfl_xor(v, off, 64);
                if (lane == 0) red_s[w][j] = v;
            }
            __syncthreads();
            if (tid < PT4)
                qs_s[tid] = 1.0f / (red_s[0][tid] + red_s[1][tid] + red_s[2][tid] + red_s[3][tid]);
            __syncthreads();
        }
        float4 er[PT4][9];
        #pragma unroll
        for (int j = 0; j < PT4; ++j) {
            int p = pt * PT4 + j;
            int s, o;
            pair_so(p, s, o);
            const float4* es = (const float4*)(ws + ENT_EMB_OFF + (size_t)(b * EE + s) * DD);
            const float4* eo = (const float4*)(ws + ENT_EMB_OFF + (size_t)(b * EE + o) * DD);
            float qs = qs_s[j];
            #pragma unroll
            for (int i4 = 0; i4 < 3; ++i4) er[j][i4] = es[i4 * 64 + lane];
            #pragma unroll
            for (int i4 = 0; i4 < 3; ++i4) er[j][3 + i4] = eo[i4 * 64 + lane];
            #pragma unroll
            for (int i4 = 0; i4 < 3; ++i4) {
                float4 sum = make_float4(0.f, 0.f, 0.f, 0.f);
                #pragma unroll
                for (int ls = 0; ls < KS; ++ls) {
                    const unsigned short* cp = (const unsigned short*)(ws + CPART_OFF) +
                                               (size_t)((ls * BB + b) * MM + p) * DD;
                    ushort4 v = *(const ushort4*)(cp + (i4 * 64 + lane) * 4);
                    sum.x += bf2f(v.x); sum.y += bf2f(v.y);
                    sum.z += bf2f(v.z); sum.w += bf2f(v.w);
                }
                er[j][6 + i4] = make_float4(sum.x * qs, sum.y * qs, sum.z * qs, sum.w * qs);
            }
        }
        int lo = (gz == 0) ? 0 : 39;
        int hi = (gz == 0) ? 39 : (RR + NN);
        for (int base = lo + w * 2; base < hi; base += 8) {
            int r1 = base + 1;
            bool has1 = (r1 < hi);
            const float4* code0 = (base < RR)
                ? (const float4*)(rel + (size_t)base * 3 * DD)
                : (const float4*)(nota + (size_t)(base - RR) * 3 * DD);
            const float4* code1 = has1
                ? ((r1 < RR) ? (const float4*)(rel + (size_t)r1 * 3 * DD)
                             : (const float4*)(nota + (size_t)(r1 - RR) * 3 * DD))
                : code0;
            float acc0[PT4] = {0.f, 0.f, 0.f, 0.f};
            float acc1[PT4] = {0.f, 0.f, 0.f, 0.f};
            #pragma unroll
            for (int i4 = 0; i4 < 9; ++i4) {
                float4 c0 = code0[i4 * 64 + lane];
                float4 c1 = code1[i4 * 64 + lane];
                #pragma unroll
                for (int j = 0; j < PT4; ++j) {
                    acc0[j] += dot4(c0, er[j][i4]);
                    acc1[j] += dot4(c1, er[j][i4]);
                }
            }
            #pragma unroll
            for (int j = 0; j < PT4; ++j) {
                float v0 = acc0[j], v1 = acc1[j];
                #pragma unroll
                for (int off = 32; off > 0; off >>= 1) {
                    v0 += __shfl_xor(v0, off, 64);
                    v1 += __shfl_xor(v1, off, 64);
                }
                if (lane == 0) {
                    int p = pt * PT4 + j;
                    if (base < RR) out[(size_t)(b * PP + p) * (RR + 1) + 1 + base] = v0;
                    else nota_s[j][base - RR] = v0;
                    if (has1) {
                        if (r1 < RR) out[(size_t)(b * PP + p) * (RR + 1) + 1 + r1] = v1;
                        else nota_s[j][r1 - RR] = v1;
                    }
                }
            }
        }
        __syncthreads();
        if (gz == 1 && tid < PT4) {
            float m = -INFINITY;
            #pragma unroll
            for (int n = 0; n < NN; ++n) m = fmaxf(m, nota_s[tid][n]);
            out[(size_t)(b * PP + pt * PT4 + tid) * (RR + 1)] = m;
        }
    }
}

extern "C" void kernel_launch(void* const* d_in, const int* in_sizes, int n_in,
                              void* d_out, int out_size, void* d_ws, size_t ws_size,
                              hipStream_t stream) {
    const float* seq   = (const float*)d_in[0];
    const float* att   = (const float*)d_in[1];
    const float* rel   = (const float*)d_in[2];
    const float* nota  = (const float*)d_in[3];
    const int*   spans = (const int*)d_in[4];
    float* ws  = (float*)d_ws;
    float* out = (float*)d_out;

    kP<<<NQBLK + NEBLK, 256, 0, stream>>>(seq, att, spans, ws);
    k3_gemm<<<dim3(MM / 64, DD / 64, KS * BB), 256, 0, stream>>>(seq, ws);
    k4_score<<<dim3(NPT4, BB, 2), 256, 0, stream>>>(rel, nota, ws, out);
}

// Round 15
// 48.696 us; speedup vs baseline: 58.0858x; 58.0858x over previous
//
#include <hip/hip_runtime.h>
#include <hip/hip_bf16.h>
#include <math.h>

// Problem dims
#define BB 2
#define LL 2048
#define DD 768
#define HH 12
#define EE 32
#define RR 57
#define NN 20
#define PP 248
#define MM 256          // P padded to 256 for MFMA tiles
#define KS 8            // K-split in context GEMM
#define KCH (LL / KS)   // 256

// ws layout (float offsets)
#define ENT_EMB_OFF 0                          // f32 B*E*D
#define A16_OFF   (BB * EE * DD)               // bf16 [B][MM][LL] (unnormalized q)
#define A16_F     (BB * MM * LL / 2)
#define CPART_OFF (A16_OFF + A16_F)            // bf16 [KS][B][MM][DD]

#define PT2 2

// kP grid roles
#define NQBLK (BB * 512)          // 1024 q blocks (4-l chunks), XCD-swizzled
#define NEBLK (EE * BB)           // 64 ent_emb blocks
#define ASTRIDE 388               // att_s row stride (floats)

typedef __attribute__((ext_vector_type(8))) short bf16x8;
typedef __attribute__((ext_vector_type(4))) float f32x4;

__device__ __forceinline__ unsigned short f2bf(float f) {
    __hip_bfloat16 h = __float2bfloat16(f);
    return __builtin_bit_cast(unsigned short, h);
}
__device__ __forceinline__ float bf2f(unsigned short u) {
    unsigned int x = ((unsigned int)u) << 16;
    return __builtin_bit_cast(float, x);
}
__device__ __forceinline__ void pair_so(int p, int& s, int& o) {
    s = p / 31;
    int r = p - s * 31;
    o = (r < s) ? r : r + 1;
}
__device__ __forceinline__ float dot4(float4 a, float4 b) {
    return a.x * b.x + a.y * b.y + a.z * b.z + a.w * b.w;
}

// ===== Kernel P: role Q (att gather -> q rows, 4-l chunks, XCD-swizzled), role E =====
__global__ __launch_bounds__(256) void kP(const float* __restrict__ seq,
                                          const float* __restrict__ att,
                                          const int* __restrict__ spans,
                                          float* __restrict__ ws) {
    __shared__ __align__(16) float att_s[4][ASTRIDE];
    __shared__ int sp_s[EE];
    int bid = blockIdx.x;
    int t = threadIdx.x;

    if (bid < NQBLK) {
        int xcd = bid & 7, i = bid >> 3;
        int chunk = xcd * (NQBLK / 8) + i;       // 0..1023
        int b = chunk >> 9, l0 = (chunk & 511) * 4;
        if (t < EE) sp_s[t] = spans[b * EE + t];
        __syncthreads();
        // 384 (e,h) rows, one 16B segment each; average the 4 w-rows inline
        for (int eh = t; eh < EE * HH; eh += 256) {
            int e = eh / HH, h = eh - e * HH;
            const float* base = att + ((size_t)(b * HH + h) * LL + sp_s[e]) * LL + l0;
            float4 v0 = *(const float4*)base;
            float4 v1 = *(const float4*)(base + LL);
            float4 v2 = *(const float4*)(base + 2 * LL);
            float4 v3 = *(const float4*)(base + 3 * LL);
            att_s[0][eh] = 0.25f * (v0.x + v1.x + v2.x + v3.x);
            att_s[1][eh] = 0.25f * (v0.y + v1.y + v2.y + v3.y);
            att_s[2][eh] = 0.25f * (v0.z + v1.z + v2.z + v3.z);
            att_s[3][eh] = 0.25f * (v0.w + v1.w + v2.w + v3.w);
        }
        __syncthreads();
        int p = t, s, o;
        pair_so(p, s, o);          // pads p>=248 -> s=8, o<=7: valid indices
        float q[4];
        #pragma unroll
        for (int l = 0; l < 4; ++l) {
            float4 a0 = *(const float4*)&att_s[l][s * HH];
            float4 a1 = *(const float4*)&att_s[l][s * HH + 4];
            float4 a2 = *(const float4*)&att_s[l][s * HH + 8];
            float4 b0 = *(const float4*)&att_s[l][o * HH];
            float4 b1 = *(const float4*)&att_s[l][o * HH + 4];
            float4 b2 = *(const float4*)&att_s[l][o * HH + 8];
            q[l] = dot4(a0, b0) + dot4(a1, b1) + dot4(a2, b2);
        }
        unsigned short* A16 = (unsigned short*)(ws + A16_OFF) + (size_t)(b * MM + p) * LL + l0;
        ushort4 ov = make_ushort4(f2bf(q[0]), f2bf(q[1]), f2bf(q[2]), f2bf(q[3]));
        *(ushort4*)A16 = ov;
    } else {
        int bx = bid - NQBLK;
        int e = bx & 31, b = bx >> 5;
        int st = spans[b * EE + e];
        float* ee = ws + ENT_EMB_OFF + (size_t)(b * EE + e) * DD;
        const float* srow = seq + (size_t)(b * LL + st) * DD;
        for (int d = t; d < DD; d += 256) {
            ee[d] = 0.25f * (srow[d] + srow[DD + d] + srow[2 * DD + d] + srow[3 * DD + d]);
        }
    }
}

// Kernel 3: cpart[ks][b][m][n] (bf16) = sum_{k in split} A[m][k] * seq[k][n]
__global__ __launch_bounds__(256) void k3_gemm(const float* __restrict__ seq,
                                               float* __restrict__ ws) {
    int m0 = blockIdx.x * 64, n0 = blockIdx.y * 64;
    int ks = blockIdx.z & (KS - 1), b = blockIdx.z >> 3;
    const unsigned short* A = (const unsigned short*)(ws + A16_OFF) + (size_t)b * MM * LL;
    __shared__ __align__(16) short As[64][40];
    __shared__ __align__(16) short Bs[64][40];
    int t = threadIdx.x;
    int row = t >> 2, seg = t & 3;
    int bl = t >> 3, bd = t & 7;
    int w = t >> 6, lane = t & 63;
    int wr = w >> 1, wc = w & 1;
    int fr = lane & 15, kb = lane >> 4;
    f32x4 acc[2][2] = {};
    int k0c = ks * KCH;
    for (int st = 0; st < KCH / 32; ++st) {
        int kk = k0c + st * 32;
        *(uint4*)&As[row][seg * 8] = *(const uint4*)(A + (size_t)(m0 + row) * LL + kk + seg * 8);
        {
            const float* sp2 = seq + (size_t)(b * LL + kk + bl) * DD + n0 + bd * 8;
            float4 u0 = *(const float4*)sp2;
            float4 u1 = *(const float4*)(sp2 + 4);
            unsigned short bv[8] = {f2bf(u0.x), f2bf(u0.y), f2bf(u0.z), f2bf(u0.w),
                                    f2bf(u1.x), f2bf(u1.y), f2bf(u1.z), f2bf(u1.w)};
            #pragma unroll
            for (int i = 0; i < 8; ++i) {
                int k = (i + bd) & 7;       // stagger: 16-way -> 2-way bank conflict
                Bs[bd * 8 + k][bl] = (short)bv[k];
            }
        }
        __syncthreads();
        bf16x8 af[2], bfr[2];
        #pragma unroll
        for (int i = 0; i < 2; ++i) af[i] = *(bf16x8*)&As[wr * 32 + i * 16 + fr][kb * 8];
        #pragma unroll
        for (int j = 0; j < 2; ++j) bfr[j] = *(bf16x8*)&Bs[wc * 32 + j * 16 + fr][kb * 8];
        #pragma unroll
        for (int i = 0; i < 2; ++i)
            #pragma unroll
            for (int j = 0; j < 2; ++j)
                acc[i][j] = __builtin_amdgcn_mfma_f32_16x16x32_bf16(af[i], bfr[j], acc[i][j], 0, 0, 0);
        __syncthreads();
    }
    unsigned short* cp =
        (unsigned short*)(ws + CPART_OFF) + (size_t)((ks * BB + b) * MM) * DD;
    #pragma unroll
    for (int i = 0; i < 2; ++i)
        #pragma unroll
        for (int j = 0; j < 2; ++j)
            #pragma unroll
            for (int r = 0; r < 4; ++r) {
                int gm = m0 + wr * 32 + i * 16 + kb * 4 + r;
                int gn = n0 + wc * 32 + j * 16 + fr;
                cp[(size_t)gm * DD + gn] = f2bf(acc[i][j][r]);
            }
}

// Kernel 4: 2 pairs/block, rows split over 4 z-groups -> 992 blocks (~4/CU)
__global__ __launch_bounds__(256) void k4_score(const float* __restrict__ rel,
                                                const float* __restrict__ nota,
                                                const float* __restrict__ ws,
                                                float* __restrict__ out) {
    int pt2 = blockIdx.x, b = blockIdx.y, gz = blockIdx.z;
    int tid = threadIdx.x, w = tid >> 6, lane = tid & 63;
    int p0 = pt2 * PT2;
    __shared__ float red_s[4][PT2];
    __shared__ float qs_s[PT2];
    __shared__ float nota_s[PT2][NN];
    // phase 0: qsum per pair (from bf16 q rows)
    {
        const unsigned short* A16 =
            (const unsigned short*)(ws + A16_OFF) + (size_t)(b * MM + p0) * LL;
        #pragma unroll
        for (int j = 0; j < PT2; ++j) {
            ushort4 u0 = *(const ushort4*)(A16 + (size_t)j * LL + tid * 8);
            ushort4 u1 = *(const ushort4*)(A16 + (size_t)j * LL + tid * 8 + 4);
            float v = bf2f(u0.x) + bf2f(u0.y) + bf2f(u0.z) + bf2f(u0.w)
                    + bf2f(u1.x) + bf2f(u1.y) + bf2f(u1.z) + bf2f(u1.w);
            #pragma unroll
            for (int off = 32; off > 0; off >>= 1) v += __shfl_xor(v, off, 64);
            if (lane == 0) red_s[w][j] = v;
        }
        __syncthreads();
        if (tid < PT2)
            qs_s[tid] = 1.0f / (red_s[0][tid] + red_s[1][tid] + red_s[2][tid] + red_s[3][tid]);
        __syncthreads();
    }
    // phase 1: per-lane emb fragments for 2 pairs (cpart bf16)
    float4 er[PT2][9];
    #pragma unroll
    for (int j = 0; j < PT2; ++j) {
        int p = p0 + j;
        int s, o;
        pair_so(p, s, o);
        const float4* es = (const float4*)(ws + ENT_EMB_OFF + (size_t)(b * EE + s) * DD);
        const float4* eo = (const float4*)(ws + ENT_EMB_OFF + (size_t)(b * EE + o) * DD);
        float qs = qs_s[j];
        #pragma unroll
        for (int i4 = 0; i4 < 3; ++i4) er[j][i4] = es[i4 * 64 + lane];
        #pragma unroll
        for (int i4 = 0; i4 < 3; ++i4) er[j][3 + i4] = eo[i4 * 64 + lane];
        #pragma unroll
        for (int i4 = 0; i4 < 3; ++i4) {
            float4 sum = make_float4(0.f, 0.f, 0.f, 0.f);
            #pragma unroll
            for (int ls = 0; ls < KS; ++ls) {
                const unsigned short* cp = (const unsigned short*)(ws + CPART_OFF) +
                                           (size_t)((ls * BB + b) * MM + p) * DD;
                ushort4 v = *(const ushort4*)(cp + (i4 * 64 + lane) * 4);
                sum.x += bf2f(v.x); sum.y += bf2f(v.y);
                sum.z += bf2f(v.z); sum.w += bf2f(v.w);
            }
            er[j][6 + i4] = make_float4(sum.x * qs, sum.y * qs, sum.z * qs, sum.w * qs);
        }
    }
    // phase 2: rows [lo,hi) for this z-group; nota rows (57..76) all in gz==3
    int lo = (gz == 0) ? 0 : (gz == 1) ? 20 : (gz == 2) ? 39 : 57;
    int hi = (gz == 0) ? 20 : (gz == 1) ? 39 : (gz == 2) ? 57 : 77;
    for (int base = lo + w * 2; base < hi; base += 8) {
        int r1 = base + 1;
        bool has1 = (r1 < hi);
        const float4* code0 = (base < RR)
            ? (const float4*)(rel + (size_t)base * 3 * DD)
            : (const float4*)(nota + (size_t)(base - RR) * 3 * DD);
        const float4* code1 = has1
            ? ((r1 < RR) ? (const float4*)(rel + (size_t)r1 * 3 * DD)
                         : (const float4*)(nota + (size_t)(r1 - RR) * 3 * DD))
            : code0;
        float acc0[PT2] = {0.f, 0.f};
        float acc1[PT2] = {0.f, 0.f};
        #pragma unroll
        for (int i4 = 0; i4 < 9; ++i4) {
            float4 c0 = code0[i4 * 64 + lane];
            float4 c1 = code1[i4 * 64 + lane];
            #pragma unroll
            for (int j = 0; j < PT2; ++j) {
                acc0[j] += dot4(c0, er[j][i4]);
                acc1[j] += dot4(c1, er[j][i4]);
            }
        }
        #pragma unroll
        for (int j = 0; j < PT2; ++j) {
            float v0 = acc0[j], v1 = acc1[j];
            #pragma unroll
            for (int off = 32; off > 0; off >>= 1) {
                v0 += __shfl_xor(v0, off, 64);
                v1 += __shfl_xor(v1, off, 64);
            }
            if (lane == 0) {
                int p = p0 + j;
                if (base < RR) out[(size_t)(b * PP + p) * (RR + 1) + 1 + base] = v0;
                else nota_s[j][base - RR] = v0;
                if (has1) {
                    if (r1 < RR) out[(size_t)(b * PP + p) * (RR + 1) + 1 + r1] = v1;
                    else nota_s[j][r1 - RR] = v1;
                }
            }
        }
    }
    __syncthreads();
    if (gz == 3 && tid < PT2) {
        float m = -INFINITY;
        #pragma unroll
        for (int n = 0; n < NN; ++n) m = fmaxf(m, nota_s[tid][n]);
        out[(size_t)(b * PP + p0 + tid) * (RR + 1)] = m;
    }
}

extern "C" void kernel_launch(void* const* d_in, const int* in_sizes, int n_in,
                              void* d_out, int out_size, void* d_ws, size_t ws_size,
                              hipStream_t stream) {
    const float* seq   = (const float*)d_in[0];
    const float* att   = (const float*)d_in[1];
    const float* rel   = (const float*)d_in[2];
    const float* nota  = (const float*)d_in[3];
    const int*   spans = (const int*)d_in[4];
    float* ws  = (float*)d_ws;
    float* out = (float*)d_out;

    kP<<<NQBLK + NEBLK, 256, 0, stream>>>(seq, att, spans, ws);
    k3_gemm<<<dim3(MM / 64, DD / 64, KS * BB), 256, 0, stream>>>(seq, ws);
    k4_score<<<dim3(PP / PT2, BB, 4), 256, 0, stream>>>(rel, nota, ws, out);
}

// Round 16
// 43.110 us; speedup vs baseline: 65.6128x; 1.1296x over previous
//
#include <hip/hip_runtime.h>
#include <hip/hip_bf16.h>
#include <math.h>

// Problem dims
#define BB 2
#define LL 2048
#define DD 768
#define D3 2304
#define HH 12
#define EE 32
#define RR 57
#define NN 20
#define PP 248
#define MM 256          // P padded to 256
#define KS 8            // K-split in context GEMM
#define KCH (LL / KS)   // 256
#define R80 80          // 77 code rows padded to 80
#define NSL 40          // score k-slices: 4 es + 4 eo + 32 c (8 ls x 4 dchunk)

// ws layout (float offsets)
#define ENT_EMB_OFF 0                           // f32 [B][EE][DD]
#define A16_OFF   (BB * EE * DD)                // bf16 [B][MM][LL]
#define A16_F     (BB * MM * LL / 2)
#define CPART_OFF (A16_OFF + A16_F)             // bf16 [KS][B][MM][DD]
#define CPART_F   (KS * BB * MM * DD / 2)
#define CODE16_OFF (CPART_OFF + CPART_F)        // bf16 [80][2304]
#define CODE16_F  (R80 * D3 / 2)
#define QSUM_OFF  (CODE16_OFF + CODE16_F)       // f32 [512] (1/qsum)
#define SPART_OFF (QSUM_OFF + 512)              // f32 [NSL][512][80]

// kP grid roles
#define NQBLK (BB * 256)          // 512 q blocks (8-l chunks), XCD-swizzled
#define NEBLK (EE * BB)           // 64 ent_emb blocks
#define NCBLK 8                   // code-cast blocks
#define ASTRIDE 388               // att_s row stride (floats)

// k3 grid roles (1D)
#define NGBLK 768                 // GEMM blocks
#define NQSB 16                   // qsum blocks (32 pairs each)

typedef __attribute__((ext_vector_type(8))) short bf16x8;
typedef __attribute__((ext_vector_type(4))) float f32x4;

__device__ __forceinline__ unsigned short f2bf(float f) {
    __hip_bfloat16 h = __float2bfloat16(f);
    return __builtin_bit_cast(unsigned short, h);
}
__device__ __forceinline__ float bf2f(unsigned short u) {
    unsigned int x = ((unsigned int)u) << 16;
    return __builtin_bit_cast(float, x);
}
__device__ __forceinline__ void pair_so(int p, int& s, int& o) {
    s = p / 31;
    int r = p - s * 31;
    o = (r < s) ? r : r + 1;
}
__device__ __forceinline__ float dot4(float4 a, float4 b) {
    return a.x * b.x + a.y * b.y + a.z * b.z + a.w * b.w;
}
__device__ __forceinline__ void cast8(float4 u0, float4 u1, short* dst) {
    ushort4 a = make_ushort4(f2bf(u0.x), f2bf(u0.y), f2bf(u0.z), f2bf(u0.w));
    ushort4 b = make_ushort4(f2bf(u1.x), f2bf(u1.y), f2bf(u1.z), f2bf(u1.w));
    *(ushort4*)dst = a;
    *(ushort4*)(dst + 4) = b;
}

// ===== Kernel P: role Q (att gather, 8-l chunks, XCD-swizzled), role E, role C (code cast) =====
__global__ __launch_bounds__(256) void kP(const float* __restrict__ seq,
                                          const float* __restrict__ att,
                                          const float* __restrict__ rel,
                                          const float* __restrict__ nota,
                                          const int* __restrict__ spans,
                                          float* __restrict__ ws) {
    __shared__ __align__(16) float att_s[8][ASTRIDE];
    __shared__ int sp_s[EE];
    int bid = blockIdx.x;
    int t = threadIdx.x;

    if (bid < NQBLK) {
        int xcd = bid & 7, i = bid >> 3;
        int chunk = xcd * (NQBLK / 8) + i;       // 0..511
        int b = chunk >> 8, l0 = (chunk & 255) * 8;
        if (t < EE) sp_s[t] = spans[b * EE + t];
        __syncthreads();
        for (int i2 = t; i2 < EE * HH * 2; i2 += 256) {
            int seg = i2 & 1, eh = i2 >> 1;
            int e = eh / HH, h = eh - e * HH;
            const float* base = att + ((size_t)(b * HH + h) * LL + sp_s[e]) * LL + l0 + seg * 4;
            float4 v0 = *(const float4*)base;
            float4 v1 = *(const float4*)(base + LL);
            float4 v2 = *(const float4*)(base + 2 * LL);
            float4 v3 = *(const float4*)(base + 3 * LL);
            att_s[seg * 4 + 0][eh] = 0.25f * (v0.x + v1.x + v2.x + v3.x);
            att_s[seg * 4 + 1][eh] = 0.25f * (v0.y + v1.y + v2.y + v3.y);
            att_s[seg * 4 + 2][eh] = 0.25f * (v0.z + v1.z + v2.z + v3.z);
            att_s[seg * 4 + 3][eh] = 0.25f * (v0.w + v1.w + v2.w + v3.w);
        }
        __syncthreads();
        int p = t, s, o;
        pair_so(p, s, o);          // pads p>=248 -> s=8, o<=7: valid indices
        float q[8];
        #pragma unroll
        for (int l = 0; l < 8; ++l) {
            float4 a0 = *(const float4*)&att_s[l][s * HH];
            float4 a1 = *(const float4*)&att_s[l][s * HH + 4];
            float4 a2 = *(const float4*)&att_s[l][s * HH + 8];
            float4 b0 = *(const float4*)&att_s[l][o * HH];
            float4 b1 = *(const float4*)&att_s[l][o * HH + 4];
            float4 b2 = *(const float4*)&att_s[l][o * HH + 8];
            q[l] = dot4(a0, b0) + dot4(a1, b1) + dot4(a2, b2);
        }
        unsigned short* A16 = (unsigned short*)(ws + A16_OFF) + (size_t)(b * MM + p) * LL + l0;
        #pragma unroll
        for (int i2 = 0; i2 < 2; ++i2) {
            ushort4 ov = make_ushort4(f2bf(q[i2 * 4 + 0]), f2bf(q[i2 * 4 + 1]),
                                      f2bf(q[i2 * 4 + 2]), f2bf(q[i2 * 4 + 3]));
            *(ushort4*)(A16 + i2 * 4) = ov;
        }
    } else if (bid < NQBLK + NEBLK) {
        int bx = bid - NQBLK;
        int e = bx & 31, b = bx >> 5;
        int st = spans[b * EE + e];
        float* ee = ws + ENT_EMB_OFF + (size_t)(b * EE + e) * DD;
        const float* srow = seq + (size_t)(b * LL + st) * DD;
        for (int d = t; d < DD; d += 256) {
            ee[d] = 0.25f * (srow[d] + srow[DD + d] + srow[2 * DD + d] + srow[3 * DD + d]);
        }
    } else {
        // role C: cast code rows (rel 0..56, nota 57..76, zeros 77..79) -> bf16
        int cid = bid - NQBLK - NEBLK;          // 0..7, 10 rows each
        unsigned short* code16 = (unsigned short*)(ws + CODE16_OFF);
        for (int idx = t; idx < 10 * (D3 / 4); idx += 256) {
            int rl = idx / (D3 / 4), dg = idx - rl * (D3 / 4);
            int r = cid * 10 + rl;
            ushort4 ov;
            if (r < RR) {
                float4 v = *(const float4*)(rel + (size_t)r * D3 + dg * 4);
                ov = make_ushort4(f2bf(v.x), f2bf(v.y), f2bf(v.z), f2bf(v.w));
            } else if (r < RR + NN) {
                float4 v = *(const float4*)(nota + (size_t)(r - RR) * D3 + dg * 4);
                ov = make_ushort4(f2bf(v.x), f2bf(v.y), f2bf(v.z), f2bf(v.w));
            } else {
                ov = make_ushort4(0, 0, 0, 0);
            }
            *(ushort4*)(code16 + (size_t)r * D3 + dg * 4) = ov;
        }
    }
}

// ===== Kernel 3 (1D grid): [0,768) context GEMM -> bf16 cpart; [768,784) qsum =====
__global__ __launch_bounds__(256) void k3_gemm(const float* __restrict__ seq,
                                               float* __restrict__ ws) {
    __shared__ __align__(16) short As[64][40];
    __shared__ __align__(16) short Bs[64][40];
    int g = blockIdx.x;
    int t = threadIdx.x;
    int w = t >> 6, lane = t & 63;

    if (g < NGBLK) {
        int m0 = (g & 3) * 64;
        int n0 = ((g >> 2) % 12) * 64;
        int z = g / 48;
        int ks = z & 7, b = z >> 3;
        const unsigned short* A = (const unsigned short*)(ws + A16_OFF) + (size_t)b * MM * LL;
        int row = t >> 2, seg = t & 3;
        int bl = t >> 3, bd = t & 7;
        int wr = w >> 1, wc = w & 1;
        int fr = lane & 15, kb = lane >> 4;
        f32x4 acc[2][2] = {};
        int k0c = ks * KCH;
        for (int st = 0; st < KCH / 32; ++st) {
            int kk = k0c + st * 32;
            *(uint4*)&As[row][seg * 8] = *(const uint4*)(A + (size_t)(m0 + row) * LL + kk + seg * 8);
            {
                const float* sp2 = seq + (size_t)(b * LL + kk + bl) * DD + n0 + bd * 8;
                float4 u0 = *(const float4*)sp2;
                float4 u1 = *(const float4*)(sp2 + 4);
                unsigned short bv[8] = {f2bf(u0.x), f2bf(u0.y), f2bf(u0.z), f2bf(u0.w),
                                        f2bf(u1.x), f2bf(u1.y), f2bf(u1.z), f2bf(u1.w)};
                #pragma unroll
                for (int i = 0; i < 8; ++i) {
                    int k = (i + bd) & 7;
                    Bs[bd * 8 + k][bl] = (short)bv[k];
                }
            }
            __syncthreads();
            bf16x8 af[2], bfr[2];
            #pragma unroll
            for (int i = 0; i < 2; ++i) af[i] = *(bf16x8*)&As[wr * 32 + i * 16 + fr][kb * 8];
            #pragma unroll
            for (int j = 0; j < 2; ++j) bfr[j] = *(bf16x8*)&Bs[wc * 32 + j * 16 + fr][kb * 8];
            #pragma unroll
            for (int i = 0; i < 2; ++i)
                #pragma unroll
                for (int j = 0; j < 2; ++j)
                    acc[i][j] = __builtin_amdgcn_mfma_f32_16x16x32_bf16(
                        af[i], bfr[j], acc[i][j], 0, 0, 0);
            __syncthreads();
        }
        unsigned short* cp =
            (unsigned short*)(ws + CPART_OFF) + (size_t)((ks * BB + b) * MM) * DD;
        #pragma unroll
        for (int i = 0; i < 2; ++i)
            #pragma unroll
            for (int j = 0; j < 2; ++j)
                #pragma unroll
                for (int r = 0; r < 4; ++r) {
                    int gm = m0 + wr * 32 + i * 16 + kb * 4 + r;
                    int gn = n0 + wc * 32 + j * 16 + fr;
                    cp[(size_t)gm * DD + gn] = f2bf(acc[i][j][r]);
                }
    } else {
        // qsum role: 32 pair-rows per block, 8 per wave
        int qb = g - NGBLK;
        const unsigned short* A16 = (const unsigned short*)(ws + A16_OFF);
        #pragma unroll
        for (int i = 0; i < 8; ++i) {
            int m = qb * 32 + w * 8 + i;
            const unsigned short* rowp = A16 + (size_t)m * LL + lane * 32;
            float v = 0.f;
            #pragma unroll
            for (int u = 0; u < 4; ++u) {
                uint4 x = *(const uint4*)(rowp + u * 8);
                const unsigned short* xs = (const unsigned short*)&x;
                #pragma unroll
                for (int e = 0; e < 8; ++e) v += bf2f(xs[e]);
            }
            #pragma unroll
            for (int off = 32; off > 0; off >>= 1) v += __shfl_xor(v, off, 64);
            if (lane == 0) ws[QSUM_OFF + m] = 1.0f / v;
        }
    }
}

// ===== Kernel 4b: score GEMM. grid (8 mtiles, 40 kslices). A gathered on the fly. =====
__global__ __launch_bounds__(256) void k4b(float* __restrict__ ws) {
    __shared__ __align__(16) short As[64][40];
    __shared__ __align__(16) short Bs[R80][40];
    int mt = blockIdx.x, sl = blockIdx.y;
    int b = mt >> 2, p0 = (mt & 3) * 64;
    int t = threadIdx.x;
    int w = t >> 6, lane = t & 63, fr = lane & 15, kb = lane >> 4;
    int row = t >> 2, sg = t & 3;
    int seg, d0, ls = 0, dgb;
    if (sl < 4)      { seg = 0; d0 = sl * 192;                              dgb = 0; }
    else if (sl < 8) { seg = 1; d0 = (sl - 4) * 192;                        dgb = DD; }
    else             { seg = 2; ls = (sl - 8) >> 2; d0 = ((sl - 8) & 3) * 192; dgb = 2 * DD; }
    int p = p0 + row, s_, o_;
    pair_so(p, s_, o_);
    int asrc = (seg == 0) ? s_ : o_;
    const unsigned short* code16 = (const unsigned short*)(ws + CODE16_OFF);
    const unsigned short* cp16 = (const unsigned short*)(ws + CPART_OFF);
    f32x4 acc[5] = {};
    for (int kk = 0; kk < 6; ++kk) {
        int d = d0 + kk * 32;
        if (seg < 2) {
            const float* src = ws + ENT_EMB_OFF + (size_t)(b * EE + asrc) * DD + d + sg * 8;
            cast8(*(const float4*)src, *(const float4*)(src + 4), &As[row][sg * 8]);
        } else {
            *(uint4*)&As[row][sg * 8] =
                *(const uint4*)(cp16 + (size_t)((ls * BB + b) * MM + p) * DD + d + sg * 8);
        }
        for (int i = t; i < R80 * 4; i += 256) {
            int br = i >> 2, bsg = i & 3;
            *(uint4*)&Bs[br][bsg * 8] =
                *(const uint4*)(code16 + (size_t)br * D3 + dgb + d + bsg * 8);
        }
        __syncthreads();
        bf16x8 af = *(bf16x8*)&As[w * 16 + fr][kb * 8];
        #pragma unroll
        for (int j = 0; j < 5; ++j) {
            bf16x8 bf = *(bf16x8*)&Bs[j * 16 + fr][kb * 8];
            acc[j] = __builtin_amdgcn_mfma_f32_16x16x32_bf16(af, bf, acc[j], 0, 0, 0);
        }
        __syncthreads();
    }
    float* sp = ws + SPART_OFF + (size_t)sl * 512 * R80 + (size_t)(mt * 64) * R80;
    #pragma unroll
    for (int j = 0; j < 5; ++j)
        #pragma unroll
        for (int r = 0; r < 4; ++r) {
            int lm = w * 16 + kb * 4 + r;
            int lr = j * 16 + fr;
            sp[(size_t)lm * R80 + lr] = acc[j][r];
        }
}

// ===== Kernel F: reduce 40 slices, apply 1/qsum to c-slices, nota max =====
__global__ __launch_bounds__(256) void kF(const float* __restrict__ ws,
                                          float* __restrict__ out) {
    __shared__ float nota_s[2][NN];
    int pt2 = blockIdx.x, b = blockIdx.y;
    int t = threadIdx.x;
    if (t < 2 * 77) {
        int j = (t < 77) ? 0 : 1;
        int r = (t < 77) ? t : t - 77;
        int p = pt2 * 2 + j;
        int m = b * MM + p;
        const float* sp = ws + SPART_OFF + (size_t)m * R80 + r;
        float raw = 0.f, csum = 0.f;
        #pragma unroll
        for (int sl = 0; sl < 8; ++sl) raw += sp[(size_t)sl * 512 * R80];
        #pragma unroll
        for (int sl = 8; sl < NSL; ++sl) csum += sp[(size_t)sl * 512 * R80];
        float v = raw + ws[QSUM_OFF + m] * csum;
        if (r < RR) out[(size_t)(b * PP + p) * (RR + 1) + 1 + r] = v;
        else nota_s[j][r - RR] = v;
    }
    __syncthreads();
    if (t < 2) {
        float mx = -INFINITY;
        #pragma unroll
        for (int n = 0; n < NN; ++n) mx = fmaxf(mx, nota_s[t][n]);
        out[(size_t)(b * PP + pt2 * 2 + t) * (RR + 1)] = mx;
    }
}

extern "C" void kernel_launch(void* const* d_in, const int* in_sizes, int n_in,
                              void* d_out, int out_size, void* d_ws, size_t ws_size,
                              hipStream_t stream) {
    const float* seq   = (const float*)d_in[0];
    const float* att   = (const float*)d_in[1];
    const float* rel   = (const float*)d_in[2];
    const float* nota  = (const float*)d_in[3];
    const int*   spans = (const int*)d_in[4];
    float* ws  = (float*)d_ws;
    float* out = (float*)d_out;

    kP<<<NQBLK + NEBLK + NCBLK, 256, 0, stream>>>(seq, att, rel, nota, spans, ws);
    k3_gemm<<<NGBLK + NQSB, 256, 0, stream>>>(seq, ws);
    k4b<<<dim3(8, NSL), 256, 0, stream>>>(ws);
    kF<<<dim3(PP / 2, BB), 256, 0, stream>>>(ws, out);
}